// Round 13
// baseline (31.638 us; speedup 1.0000x reference)
//
#include <hip/hip_runtime.h>
#include <math.h>

// Problem constants: N=12000, NEI=32, K=8, D=64
#define NPTS 12000
#define NNEI 32
#define KK   8
#define DD   64

// Round 13 (= R12 + occupancy push):
//  - __launch_bounds__(512, 3) on passA. On this toolchain the 2nd arg acts
//    as WORKGROUPS/CU (R7 evidence: (512,6) -> 40 VGPR = 512/12): (512,3)
//    -> 24 waves/CU -> 6 waves/SIMD -> VGPR cap ~85 -> 3 blocks/CU resident
//    (was 2 at ~96 live VGPR), +50% latency hiding.
//  - W fragment loads moved inside the per-nt MFMA loop so the register
//    allocator can stay under the cap without spilling (u0..u3 die before
//    the MFMAs; compiler pipelines as pressure allows).
// Everything else identical to R12.

typedef __bf16 bf16x8 __attribute__((ext_vector_type(8)));
typedef float  f32x4  __attribute__((ext_vector_type(4)));

#define MFMA16(A, B, C) __builtin_amdgcn_mfma_f32_16x16x32_bf16((A), (B), (C), 0, 0, 0)

__device__ __forceinline__ void pack8(float4 u, float4 v, bf16x8& h, bf16x8& l) {
    float a[8] = {u.x, u.y, u.z, u.w, v.x, v.y, v.z, v.w};
    #pragma unroll
    for (int i = 0; i < 8; ++i) {
        __bf16 hh = (__bf16)a[i];
        h[i] = hh;
        l[i] = (__bf16)(a[i] - (float)hh);
    }
}

__device__ __forceinline__ float dot4(float4 a, float4 b) {
    return a.x * b.x + a.y * b.y + a.z * b.z + a.w * b.w;
}

// ---------------------------------------------------------------- packW ----
// 8 blocks x 512. Block b packs W fragments for kernel k=b. Block 0 also:
// kmF[k][d] = (kernels*metric)[k][d] (f32), esA[k] = exp(scales[k]).
__launch_bounds__(512)
__global__ void packW_kernel(const float* __restrict__ W,
                             const float* __restrict__ kp,
                             const float* __restrict__ scales,
                             bf16x8* __restrict__ Wpk,
                             float*  __restrict__ kmF,
                             float*  __restrict__ esA) {
    const int t    = threadIdx.x;
    const int id   = blockIdx.x * 512 + t;   // 0..4095
    const int lane = id & 63;
    const int ks   = (id >> 6) & 1;
    const int nt   = (id >> 7) & 3;
    const int k    = id >> 9;
    const int c    = lane & 15;
    const int g    = lane >> 4;

    // ---- W fragment pack (all 8 blocks) ----
    const float* wr = W + ((size_t)k * DD + nt * 16 + c) * DD + ks * 32 + g * 8;
    bf16x8 h, l;
    pack8(*(const float4*)wr, *(const float4*)(wr + 4), h, l);
    const size_t base = ((((size_t)k * 4 + nt) * 2 + ks) * 2) * 64 + lane;
    Wpk[base]      = h;   // hi plane
    Wpk[base + 64] = l;   // lo plane

    // ---- block 0: km rows (f32) + esA ----
    if (blockIdx.x == 0) {
        const int w  = t >> 6;      // wave index = kernel row
        const int ln = t & 63;
        float spv = (ln == 0) ? 0.f : kp[w * DD + ln];   // kp[:,0]==0
        float ss = spv * spv;
        #pragma unroll
        for (int off = 32; off > 0; off >>= 1) ss += __shfl_xor(ss, off);
        float nrm = sqrtf(fmaxf(ss, 1e-8f));
        float e  = __expf(nrm);
        float ei = 1.0f / e;
        float ch = 0.5f * (e + ei);
        float sh = 0.5f * (e - ei);
        kmF[w * DD + ln] = (ln == 0) ? ch : -(sh / nrm) * spv;  // kernels*metric
        if (t < KK) esA[t] = __expf(scales[t]);
    }
}

// ---------------------------------------------------------------- pass A ---
__launch_bounds__(512, 3)   // 3 workgroups/CU (R7: 2nd arg = wg/CU) -> VGPR<=~85
__global__ void passA_kernel(const float* __restrict__ x,
                             const bf16x8* __restrict__ Wpk,
                             const float* __restrict__ kmF,
                             const float* __restrict__ esA,
                             const float* __restrict__ b,
                             float* __restrict__ F) {
    __shared__ float xtr[KK][16][68];   // stride 68: write/read both 2-way (free)
    __shared__ float disl[16][12];      // holds u = 1/z per (point, k)

    const int t    = threadIdx.x;
    const int k    = t >> 6;            // wave index == kernel index
    const int lane = t & 63;
    const int c    = lane & 15;
    const int g    = lane >> 4;
    const int pbase = blockIdx.x * 16;

    const float es = esA[k];
    float bnt[4];
    #pragma unroll
    for (int nt = 0; nt < 4; ++nt) bnt[nt] = b[k * DD + nt * 16 + c];

    // ---- x row chunks (16 floats, live only until pack) ----
    float4 u0, u1, u2, u3;
    {
        const float* xr = x + (size_t)(pbase + c) * DD + g * 8;
        u0 = *(const float4*)(xr +  0);
        u1 = *(const float4*)(xr +  4);
        u2 = *(const float4*)(xr + 32);
        u3 = *(const float4*)(xr + 36);
    }

    // ---- inner product <x_row, km_k>; softmax numerator u = 1/z (exact) ----
    {
        const float4* km4 = (const float4*)(kmF + k * DD);
        float ip = dot4(u0, km4[g * 2 + 0]) + dot4(u1, km4[g * 2 + 1])
                 + dot4(u2, km4[g * 2 + 8]) + dot4(u3, km4[g * 2 + 9]);
        ip += __shfl_xor(ip, 16);
        ip += __shfl_xor(ip, 32);   // all 4 g-groups summed; lanes with same c agree
        if (g == 0) {
            float nc = fmaxf(ip, 1.0f + 1e-7f);
            // exp(-arccosh(nc)) = 1 / (nc + sqrt(nc^2 - 1))  -- exact
            disl[c][k] = 1.0f / (nc + sqrtf(nc * nc - 1.0f));
        }
    }

    // ---- A fragments (u0..u3 die here) ----
    bf16x8 Ah[2], Al[2];
    pack8(u0, u1, Ah[0], Al[0]);
    pack8(u2, u3, Ah[1], Al[1]);

    // ---- MFMAs: Y only (24); W fragments loaded per-nt under the VGPR cap ----
    f32x4 accY[4];
    #pragma unroll
    for (int nt = 0; nt < 4; ++nt) accY[nt] = (f32x4){0.f, 0.f, 0.f, 0.f};
    #pragma unroll
    for (int nt = 0; nt < 4; ++nt) {
        #pragma unroll
        for (int ks = 0; ks < 2; ++ks) {
            const size_t base = ((((size_t)k * 4 + nt) * 2 + ks) * 2) * 64 + lane;
            bf16x8 wh = Wpk[base];
            bf16x8 wl = Wpk[base + 64];
            bf16x8 ah = Ah[ks], al = Al[ks];
            accY[nt] = MFMA16(ah, wh, accY[nt]);
            accY[nt] = MFMA16(ah, wl, accY[nt]);
            accY[nt] = MFMA16(al, wh, accY[nt]);
        }
    }

    // ---- epilogue: per-point stats (C layout: row p=g*4+rr, col o=nt*16+c) ----
    float yv[4][4], sall[4];
    #pragma unroll
    for (int rr = 0; rr < 4; ++rr) {
        float s = 0.f;
        #pragma unroll
        for (int nt = 0; nt < 4; ++nt) {
            float y = accY[nt][rr] + bnt[nt];
            yv[nt][rr] = y;
            s += y * y;
        }
        sall[rr] = s;
    }
    #pragma unroll
    for (int m = 1; m <= 8; m <<= 1)
        #pragma unroll
        for (int rr = 0; rr < 4; ++rr) sall[rr] += __shfl_xor(sall[rr], m);
    float y0[4];
    #pragma unroll
    for (int rr = 0; rr < 4; ++rr) y0[rr] = __shfl(yv[0][rr], lane & 48);

    #pragma unroll
    for (int rr = 0; rr < 4; ++rr) {
        const int p = g * 4 + rr;
        float nar2 = fmaxf(sall[rr] - y0[rr] * y0[rr], 1e-8f);
        float time = es / (1.0f + __expf(-y0[rr])) + 1.0001f;
        float s3   = sqrtf((time * time - 1.0f) / nar2);
        #pragma unroll
        for (int nt = 0; nt < 4; ++nt) {
            float v = yv[nt][rr] * s3;
            if (nt == 0 && c == 0) v = time;
            xtr[k][p][nt * 16 + c] = v;
        }
    }
    __syncthreads();

    // ---- combine: wave k handles points {2k, 2k+1} ----
    #pragma unroll
    for (int pi = 0; pi < 2; ++pi) {
        const int p = k * 2 + pi;
        float uk[KK];
        float sum = 0.f;
        #pragma unroll
        for (int q = 0; q < KK; ++q) { uk[q] = disl[p][q]; sum += uk[q]; }
        float inv = 1.0f / sum;
        float agg = 0.f;
        #pragma unroll
        for (int q = 0; q < KK; ++q) agg += uk[q] * inv * xtr[q][p][lane];

        float vv = (lane == 0) ? -agg * agg : agg * agg;
        #pragma unroll
        for (int m = 32; m > 0; m >>= 1) vv += __shfl_xor(vv, m);
        float den = sqrtf(fmaxf(fabsf(vv), 1e-8f));
        F[(size_t)(pbase + p) * DD + lane] = agg / den;
    }
}

// ---------------------------------------------------------------- pass B ---
__launch_bounds__(256)
__global__ void passB_kernel(const float* __restrict__ F,
                             const int* __restrict__ nei,
                             const int* __restrict__ mask,
                             float* __restrict__ out) {
    const int t    = threadIdx.x;
    const int wave = t >> 6;
    const int lane = t & 63;
    const int c    = lane & 15;   // col quad: o = 4c..4c+3
    const int g    = lane >> 4;   // m sub-index
    const int n    = blockIdx.x * 4 + wave;

    // one coalesced 256B fetch per wave: lanes 0..31 nei row, 32..63 mask row
    int vsrc;
    if (lane < 32) vsrc = nei[n * NNEI + lane];
    else           vsrc = mask[n * NNEI + (lane - 32)];

    const float4* F4 = (const float4*)F;
    float4 acc = {0.f, 0.f, 0.f, 0.f};
    #pragma unroll
    for (int mq = 0; mq < 8; ++mq) {
        int   m   = mq * 4 + g;
        int   j   = __shfl(vsrc, m);
        float wgt = (float)__shfl(vsrc, 32 + m) + 1e-4f;
        float4 v  = F4[(size_t)j * 16 + c];
        acc.x += wgt * v.x; acc.y += wgt * v.y;
        acc.z += wgt * v.z; acc.w += wgt * v.w;
    }
    // reduce over the 4 m-subgroups (lanes xor 16, 32)
    #pragma unroll
    for (int m = 16; m <= 32; m <<= 1) {
        acc.x += __shfl_xor(acc.x, m); acc.y += __shfl_xor(acc.y, m);
        acc.z += __shfl_xor(acc.z, m); acc.w += __shfl_xor(acc.w, m);
    }
    // lorentz inner: minus sign on o==0 (lane c==0, component .x)
    float s = acc.x * acc.x + acc.y * acc.y + acc.z * acc.z + acc.w * acc.w;
    if (c == 0) s -= 2.0f * acc.x * acc.x;
    #pragma unroll
    for (int m = 1; m <= 8; m <<= 1) s += __shfl_xor(s, m);
    float den = sqrtf(fmaxf(fabsf(s), 1e-8f));
    if (g == 0) {
        float4 rr = {acc.x / den, acc.y / den, acc.z / den, acc.w / den};
        ((float4*)out)[(size_t)n * 16 + c] = rr;
    }
}

// ---------------------------------------------------------------- launch ---
extern "C" void kernel_launch(void* const* d_in, const int* in_sizes, int n_in,
                              void* d_out, int out_size, void* d_ws, size_t ws_size,
                              hipStream_t stream) {
    const float* x      = (const float*)d_in[0];  // (12000, 64) f32
    const int*   nei    = (const int*)  d_in[1];  // (12000, 32) int32
    const int*   mask   = (const int*)  d_in[2];  // (12000, 32) int32
    const float* kp     = (const float*)d_in[3];  // (8, 64) f32
    const float* W      = (const float*)d_in[4];  // (8, 64, 64) f32
    const float* b      = (const float*)d_in[5];  // (8, 64) f32
    const float* scales = (const float*)d_in[6];  // (8,) f32
    float*       out    = (float*)d_out;          // (12000, 64) f32

    // ws: F (N*D f32) ; Wpk (8192 bf16x8 = 128KB) ; kmF (512 f32) ; esA (8 f32)
    const size_t needed = (size_t)(NPTS * DD) * sizeof(float)
                        + 8192 * 16 + (512 + 8) * sizeof(float);
    if (ws_size < needed) return;
    float*  F   = (float*)d_ws;
    bf16x8* Wpk = (bf16x8*)(F + (size_t)NPTS * DD);
    float*  kmF = (float*)(Wpk + 8192);
    float*  esA = kmF + 512;

    packW_kernel<<<8, 512, 0, stream>>>(W, kp, scales, Wpk, kmF, esA);
    passA_kernel<<<NPTS / 16, 512, 0, stream>>>(x, Wpk, kmF, esA, b, F);
    passB_kernel<<<NPTS / 4, 256, 0, stream>>>(F, nei, mask, out);
}